// Round 6
// baseline (13.769 us; speedup 1.0000x reference)
//
#include <hip/hip_runtime.h>
#include <math.h>

#define KROOTS 16
#define NC 17        // K+1 coefficients
#define BLK 256      // threads per block

// Real-parts-only output (17 floats/row), fully LDS-staged I/O:
//  - input: cooperative lane-contiguous float4 load of block's 16 KB -> LDS
//  - output: rows staged in LDS (stride 17 floats, odd -> conflict-free),
//    then cooperative lane-contiguous float4 store of block's 17,408 B
// MODE 0 fallback (interleaved re/im) kept for layout safety.
template <int MODE>
__global__ __launch_bounds__(BLK) void encoder_vieta_kernel(
    const float* __restrict__ x,
    const float* __restrict__ shuffle,
    float* __restrict__ out,
    int B)
{
    __shared__ float sc[KROOTS], ss[KROOTS];
    __shared__ float sbuf[BLK * NC];   // 17,408 B; input staging overlays output staging

    const int tid = threadIdx.x;
    const size_t blk_row0 = (size_t)blockIdx.x * BLK;

    if (tid < KROOTS) {
        float phi = shuffle[tid];
        sc[tid] = cosf(phi);
        ss[tid] = sinf(phi);
    }

    // ---- coalesced input staging: 1024 float4, lane-contiguous ----
    {
        const float4* xg = reinterpret_cast<const float4*>(x + blk_row0 * KROOTS);
        float4* sb4 = reinterpret_cast<float4*>(sbuf);
        #pragma unroll
        for (int i = 0; i < BLK * KROOTS / 4 / BLK; ++i)   // 4 iters
            sb4[tid + BLK * i] = xg[tid + BLK * i];
    }
    __syncthreads();

    // per-thread row read from LDS (4x ds_read_b128, ~8-way conflict, negligible)
    float xr[KROOTS];
    {
        const float4* sb4 = reinterpret_cast<const float4*>(sbuf);
        #pragma unroll
        for (int i = 0; i < 4; ++i) {
            float4 v = sb4[tid * 4 + i];
            xr[4 * i + 0] = v.x;
            xr[4 * i + 1] = v.y;
            xr[4 * i + 2] = v.z;
            xr[4 * i + 3] = v.w;
        }
    }

    // R = sqrt(1 + sin(pi/16)) (learnable_radius=False)
    const float R    = 1.09320186720915563f;
    const float invR = 0.91474476120342423f;

    // Vieta: c[d] -= r * c[d-1], d descending. Static indices -> VGPRs.
    float cr[NC], ci[NC];
    cr[0] = 1.0f; ci[0] = 0.0f;
    #pragma unroll
    for (int d = 1; d < NC; ++d) { cr[d] = 0.0f; ci[d] = 0.0f; }

    #pragma unroll
    for (int j = 0; j < KROOTS; ++j) {
        const float rad = (xr[j] > 0.0f) ? R : invR;
        const float rr = rad * sc[j];
        const float ri = rad * ss[j];
        #pragma unroll
        for (int d = j + 1; d >= 1; --d) {
            const float ar = cr[d - 1], ai = ci[d - 1];
            cr[d] = fmaf(-rr, ar, fmaf( ri, ai, cr[d]));
            ci[d] = fmaf(-rr, ai, fmaf(-ri, ar, ci[d]));
        }
    }

    // Row L2 norm over complex magnitudes; target norm sqrt(K+1)
    float sum = 0.0f;
    #pragma unroll
    for (int d = 0; d < NC; ++d)
        sum = fmaf(cr[d], cr[d], fmaf(ci[d], ci[d], sum));
    const float scale = sqrtf(17.0f) * __frsqrt_rn(sum);

    if (MODE == 0) {
        const int b = (int)blk_row0 + tid;
        if (b < B) {
            float2* op = reinterpret_cast<float2*>(out + (size_t)b * 2 * NC);
            #pragma unroll
            for (int d = 0; d < NC; ++d)
                op[d] = make_float2(cr[d] * scale, ci[d] * scale);
        }
    } else {
        // all threads done reading input staging before overwrite
        __syncthreads();
        // stage real parts: stride 17 floats (odd -> 2 lanes/bank, free)
        #pragma unroll
        for (int d = 0; d < NC; ++d)
            sbuf[tid * NC + d] = cr[d] * scale;
        __syncthreads();

        // cooperative contiguous float4 store of block's 17,408 B region
        float4* og = reinterpret_cast<float4*>(out + blk_row0 * NC);
        const float4* sg = reinterpret_cast<const float4*>(sbuf);
        #pragma unroll
        for (int i = tid; i < BLK * NC / 4; i += BLK)   // 1088 f4, 4.25/thread
            og[i] = sg[i];
    }
}

extern "C" void kernel_launch(void* const* d_in, const int* in_sizes, int n_in,
                              void* d_out, int out_size, void* d_ws, size_t ws_size,
                              hipStream_t stream) {
    const float* x       = (const float*)d_in[0];
    const float* shuffle = (const float*)d_in[1];
    float* out = (float*)d_out;
    const int B = in_sizes[0] / KROOTS;
    const int grid = (B + BLK - 1) / BLK;
    if (out_size >= 2 * NC * B) {
        encoder_vieta_kernel<0><<<grid, BLK, 0, stream>>>(x, shuffle, out, B);
    } else {
        encoder_vieta_kernel<1><<<grid, BLK, 0, stream>>>(x, shuffle, out, B);
    }
}

// Round 7
// 13.146 us; speedup vs baseline: 1.0474x; 1.0474x over previous
//
#include <hip/hip_runtime.h>
#include <math.h>

#define KROOTS 16
#define NC 17        // K+1 coefficients
#define BLK 64       // ONE wave per block: s_barrier is a no-op, waves decoupled

// Real-parts-only output (17 floats/row).
//  - input: direct per-thread float4 loads (R6 showed staging these is null)
//  - output: per-wave LDS staging (stride 17 floats, odd -> conflict-free),
//    then lane-contiguous float4 store of the wave's 4,352 B region
// MODE 0 fallback (interleaved re/im) kept for layout safety.
template <int MODE>
__global__ __launch_bounds__(BLK) void encoder_vieta_kernel(
    const float* __restrict__ x,
    const float* __restrict__ shuffle,
    float* __restrict__ out,
    int B)
{
    __shared__ float sc[KROOTS], ss[KROOTS];
    __shared__ float so[BLK * NC];   // 4,352 B per-wave store staging

    const int tid = threadIdx.x;
    if (tid < KROOTS) {
        float phi = shuffle[tid];
        sc[tid] = cosf(phi);
        ss[tid] = sinf(phi);
    }
    __syncthreads();   // 1-wave block: compiles to waitcnt only, no real barrier

    const int b = blockIdx.x * BLK + tid;
    if (b >= B) return;   // B % 64 == 0 for this problem, uniform

    // R = sqrt(1 + sin(pi/16)) (learnable_radius=False)
    const float R    = 1.09320186720915563f;
    const float invR = 0.91474476120342423f;

    // direct row load: 4x float4 (64 B/thread)
    const float4* xp = reinterpret_cast<const float4*>(x + (size_t)b * KROOTS);
    float xr[KROOTS];
    #pragma unroll
    for (int i = 0; i < 4; ++i) {
        float4 v = xp[i];
        xr[4 * i + 0] = v.x;
        xr[4 * i + 1] = v.y;
        xr[4 * i + 2] = v.z;
        xr[4 * i + 3] = v.w;
    }

    // Vieta: c[d] -= r * c[d-1], d descending. Static indices -> VGPRs.
    float cr[NC], ci[NC];
    cr[0] = 1.0f; ci[0] = 0.0f;
    #pragma unroll
    for (int d = 1; d < NC; ++d) { cr[d] = 0.0f; ci[d] = 0.0f; }

    #pragma unroll
    for (int j = 0; j < KROOTS; ++j) {
        const float rad = (xr[j] > 0.0f) ? R : invR;
        const float rr = rad * sc[j];
        const float ri = rad * ss[j];
        #pragma unroll
        for (int d = j + 1; d >= 1; --d) {
            const float ar = cr[d - 1], ai = ci[d - 1];
            cr[d] = fmaf(-rr, ar, fmaf( ri, ai, cr[d]));
            ci[d] = fmaf(-rr, ai, fmaf(-ri, ar, ci[d]));
        }
    }

    // Row L2 norm over complex magnitudes; target norm sqrt(K+1)
    float sum = 0.0f;
    #pragma unroll
    for (int d = 0; d < NC; ++d)
        sum = fmaf(cr[d], cr[d], fmaf(ci[d], ci[d], sum));
    const float scale = sqrtf(17.0f) * __frsqrt_rn(sum);

    if (MODE == 0) {
        float2* op = reinterpret_cast<float2*>(out + (size_t)b * 2 * NC);
        #pragma unroll
        for (int d = 0; d < NC; ++d)
            op[d] = make_float2(cr[d] * scale, ci[d] * scale);
    } else {
        // stage real parts: stride 17 floats (odd -> 2 lanes/bank, free)
        #pragma unroll
        for (int d = 0; d < NC; ++d)
            so[tid * NC + d] = cr[d] * scale;
        __syncthreads();   // 1-wave: lgkmcnt wait only

        // lane-contiguous float4 store of this wave's 4,352 B region
        const size_t blk_f4 = (size_t)blockIdx.x * (BLK * NC / 4);
        float4* og = reinterpret_cast<float4*>(out) + blk_f4;
        const float4* sg = reinterpret_cast<const float4*>(so);
        #pragma unroll
        for (int i = tid; i < BLK * NC / 4; i += BLK)   // 272 f4 -> 4.25/thread
            og[i] = sg[i];
    }
}

extern "C" void kernel_launch(void* const* d_in, const int* in_sizes, int n_in,
                              void* d_out, int out_size, void* d_ws, size_t ws_size,
                              hipStream_t stream) {
    const float* x       = (const float*)d_in[0];
    const float* shuffle = (const float*)d_in[1];
    float* out = (float*)d_out;
    const int B = in_sizes[0] / KROOTS;
    const int grid = (B + BLK - 1) / BLK;
    if (out_size >= 2 * NC * B) {
        encoder_vieta_kernel<0><<<grid, BLK, 0, stream>>>(x, shuffle, out, B);
    } else {
        encoder_vieta_kernel<1><<<grid, BLK, 0, stream>>>(x, shuffle, out, B);
    }
}